// Round 13
// baseline (351.661 us; speedup 1.0000x reference)
//
#include <hip/hip_runtime.h>

typedef unsigned int u32;
typedef unsigned short u16;

typedef __attribute__((ext_vector_type(8))) short bf16x8;
typedef __attribute__((ext_vector_type(4))) float f32x4;

__device__ __forceinline__ u16 f2bf(float f) {
  u32 u = __builtin_bit_cast(u32, f);
  u32 r = (u + 0x7fffu + ((u >> 16) & 1u)) >> 16;  // RNE
  return (u16)r;
}
__device__ __forceinline__ float bfl(u32 u) { return __builtin_bit_cast(float, u << 16); }
__device__ __forceinline__ float bfh(u32 u) { return __builtin_bit_cast(float, u & 0xffff0000u); }

__device__ __forceinline__ void gload_lds16(const u16* g, u16* l) {
  __builtin_amdgcn_global_load_lds(
      (const __attribute__((address_space(1))) void*)g,
      (__attribute__((address_space(3))) void*)l, 16, 0, 0);
}

// ---------------------------------------------------------------------------
// W_qkv [1536,4608] f32 -> Wt [4608,1536] bf16  (64x64 tiles, float4 I/O)
// ---------------------------------------------------------------------------
__global__ __launch_bounds__(256) void transp_wt(const float* __restrict__ W,
                                                 u16* __restrict__ Wt) {
  __shared__ float tile[64][68];
  int bk = blockIdx.x % 24, bn = blockIdx.x / 24;
  int k0 = bk * 64, n0 = bn * 64;
  int tid = threadIdx.x;
#pragma unroll
  for (int p = 0; p < 4; p++) {
    int idx = p * 256 + tid;
    int r = idx >> 4, c4 = idx & 15;
    *(float4*)&tile[r][c4 * 4] = *(const float4*)&W[(size_t)(k0 + r) * 4608 + n0 + c4 * 4];
  }
  __syncthreads();
#pragma unroll
  for (int p = 0; p < 2; p++) {
    int idx = p * 256 + tid;
    int rn = idx >> 3, kc = idx & 7;
    u16 pk[8];
#pragma unroll
    for (int e = 0; e < 8; e++) pk[e] = f2bf(tile[kc * 8 + e][rn]);
    *(uint4*)&Wt[(size_t)(n0 + rn) * 1536 + k0 + kc * 8] = *(const uint4*)pk;
  }
}

// ---------------------------------------------------------------------------
// X [16384*1536] f32 -> bf16
// ---------------------------------------------------------------------------
__global__ __launch_bounds__(256) void conv_x(const float* __restrict__ X,
                                              u16* __restrict__ Xb) {
  int i = blockIdx.x * 256 + threadIdx.x;
  const float4* xp = (const float4*)X;
  float4 a = xp[i * 2], b = xp[i * 2 + 1];
  uint4 o;
  o.x = (u32)f2bf(a.x) | ((u32)f2bf(a.y) << 16);
  o.y = (u32)f2bf(a.z) | ((u32)f2bf(a.w) << 16);
  o.z = (u32)f2bf(b.x) | ((u32)f2bf(b.y) << 16);
  o.w = (u32)f2bf(b.z) | ((u32)f2bf(b.w) << 16);
  ((uint4*)Xb)[i] = o;
}

// ---------------------------------------------------------------------------
// pos-emb stage 1: partial sums over 32-wide k-slices; W_pos read ONCE.
// ---------------------------------------------------------------------------
__global__ __launch_bounds__(256) void pos_emb_part(const float* __restrict__ Wp,
                                                    float* __restrict__ part) {
  __shared__ float er[13 * 32];
  int ks = blockIdx.x % 48, nb = blockIdx.x / 48;
  int tid = threadIdx.x;
  int n = nb * 256 + tid;
  const float cfreq = 9.210340371976184f / 767.0f;  // ln(10000)/(nts-1)
  for (int i = tid; i < 13 * 32; i += 256) {  // strided (R6 bug lesson)
    int f = i >> 5, kk = i & 31;
    int k = ks * 32 + kk;
    int ii = (k < 768) ? k : (k - 768);
    float fr = expf(-cfreq * (float)ii);
    float st = (float)(12 - f) * fr;
    er[f * 32 + kk] = (k < 768) ? sinf(st) : cosf(st);
  }
  __syncthreads();
  float acc[13];
#pragma unroll
  for (int f = 0; f < 13; f++) acc[f] = 0.f;
  const float* wp = Wp + (size_t)(ks * 32) * 1536 + n;
  for (int kk = 0; kk < 32; kk++) {
    float w = wp[(size_t)kk * 1536];
#pragma unroll
    for (int f = 0; f < 13; f++) acc[f] = fmaf(er[f * 32 + kk], w, acc[f]);
  }
#pragma unroll
  for (int f = 0; f < 13; f++)
    part[((size_t)ks * 13 + f) * 1536 + n] = acc[f];
}

// ---------------------------------------------------------------------------
// pos-emb stage 2: reduce 48 slices -> sembbf [16,1536] bf16 (rows 13..15 = 0)
// ---------------------------------------------------------------------------
__global__ __launch_bounds__(256) void pos_emb_red(const float* __restrict__ part,
                                                   u16* __restrict__ sembbf) {
  int idxg = blockIdx.x * 256 + threadIdx.x;  // < 24576
  int f = idxg / 1536, n = idxg % 1536;
  float s = 0.f;
  if (f < 13)
    for (int ks = 0; ks < 48; ks++)
      s += part[((size_t)ks * 13 + f) * 1536 + n];
  sembbf[idxg] = f2bf(s);
}

// ---------------------------------------------------------------------------
// qkv = Xb @ Wt^T : R13. Calibrated model (R12 hit 100% of its ceiling after
// tail correction; m201 cross-check 60.6% pred vs 62.1% meas):
//   duration = block LDS bytes/k / 256 B/cyc;  util = FLOP-per-LDS-byte/52.8.
// R12 block (256x128): 28.4 FLOP/B -> 53.8% ceiling, measured 48.5 with 11%
// grid tail (2304 blocks / 512 slots = 4.5 rounds).
// R13: block 128x288, 4 waves (2Mx2N -> wave 64x144):
//   bytes/k = 2*(128*2 + 288*2 + 416) = 2496; FLOP/k = 73728 -> 29.5 FLOP/B
//   -> 56.0% ceiling, AND grid 128bm x 16bn = 2048 = 4.0 EXACT rounds.
// Regs: acc[4][9] = 144 AGPR + af[4]+bfr[9] = 52 VGPR ~= 230 <= 256 (2 w/SIMD).
// LDS: A dbuf 2x[128][64] (32 KB) @0; B single [288][64] (36 KB) @16384 u16;
// epilogue repack [128][296] -> alloc 75776 B -> 2 blocks/CU (151.5 KB).
// Schedule/tile t (R12's proven scheme, A/B roles swapped):
//   stage A(t+1) (cross-parity, WAR-safe) ; read af/bfr ks0 ; MFMA ks0 ;
//   read af/bfr ks1 ; lgkmcnt(0)+barrier ; stage B(t+1) over B-buf ;
//   MFMA ks1 ; vmcnt(0)+barrier.  Co-resident block hides residual stalls.
// ---------------------------------------------------------------------------
__global__ __launch_bounds__(256, 2) void gemm_qkv(const u16* __restrict__ Xb,
                                                   const u16* __restrict__ Bt,
                                                   u16* __restrict__ C,
                                                   const float* __restrict__ pds) {
  extern __shared__ u16 smem[];

  const int tid = threadIdx.x;   // 0..255
  const int lane = tid & 63;
  const int wv = tid >> 6;       // 0..3
  const int wr = wv >> 1;        // 0..1  m-half (64 rows)
  const int wc = wv & 1;         // 0..1  n-half (144 cols)
  const int lr = lane & 15;
  const int lkq = lane >> 4;     // 0..3
  const int sx = lr & 7;         // proven swizzle (R5/R8/R9/R12)

  // 2048 blocks = 8 xcd x (16 bm x 16 bn), bn fastest (A-slice L2-resident)
  int bid = blockIdx.x;
  int xcd = bid & 7, idx = bid >> 3;
  int bm = xcd * 16 + idx / 16;
  int bn = idx % 16;
  int m0 = bm * 128, n0 = bn * 288;

  auto stageA = [&](int T) {  // 128 rows x 8 chunks = 1024, 4 loads/thread
#pragma unroll
    for (int q = 0; q < 4; q++) {
      int ch = q * 256 + tid;
      int r = ch >> 3, cr = ch & 7;
      int crs = cr ^ (r & 7);
      gload_lds16(Xb + (size_t)(m0 + r) * 1536 + T * 64 + crs * 8,
                  smem + (T & 1) * 8192 + ch * 8);
    }
  };
  auto stageB = [&](int T) {  // 288 rows x 8 chunks = 2304, 9 loads/thread
#pragma unroll
    for (int q = 0; q < 9; q++) {
      int ch = q * 256 + tid;
      int r = ch >> 3, cr = ch & 7;
      int crs = cr ^ (r & 7);
      gload_lds16(Bt + (size_t)(n0 + r) * 1536 + T * 64 + crs * 8,
                  smem + 16384 + ch * 8);
    }
  };

  f32x4 acc[4][9];
#pragma unroll
  for (int i = 0; i < 4; i++)
#pragma unroll
    for (int j = 0; j < 9; j++) acc[i][j] = (f32x4){0.f, 0.f, 0.f, 0.f};

  stageA(0); stageB(0);
  asm volatile("s_waitcnt vmcnt(0)" ::: "memory");
  __builtin_amdgcn_s_barrier();

  for (int t = 0; t < 24; t++) {
    const int ab = (t & 1) * 8192;

    if (t < 23) stageA(t + 1);  // cross-parity, WAR-safe, long latency cover

    bf16x8 af[4], bfr[9];
    // ---- ks0 frags + MFMA
#pragma unroll
    for (int i = 0; i < 4; i++) {
      int R = wr * 64 + i * 16 + lr;
      af[i] = *(const bf16x8*)&smem[ab + R * 64 + (lkq ^ sx) * 8];
    }
#pragma unroll
    for (int j = 0; j < 9; j++) {
      int R = wc * 144 + j * 16 + lr;
      bfr[j] = *(const bf16x8*)&smem[16384 + R * 64 + (lkq ^ sx) * 8];
    }
    __builtin_amdgcn_s_setprio(1);
#pragma unroll
    for (int i = 0; i < 4; i++)
#pragma unroll
      for (int j = 0; j < 9; j++)
        acc[i][j] = __builtin_amdgcn_mfma_f32_16x16x32_bf16(af[i], bfr[j], acc[i][j], 0, 0, 0);
    __builtin_amdgcn_s_setprio(0);

    // ---- ks1 frags to regs, then free the B buffer
#pragma unroll
    for (int i = 0; i < 4; i++) {
      int R = wr * 64 + i * 16 + lr;
      af[i] = *(const bf16x8*)&smem[ab + R * 64 + ((4 + lkq) ^ sx) * 8];
    }
#pragma unroll
    for (int j = 0; j < 9; j++) {
      int R = wc * 144 + j * 16 + lr;
      bfr[j] = *(const bf16x8*)&smem[16384 + R * 64 + ((4 + lkq) ^ sx) * 8];
    }
    asm volatile("s_waitcnt lgkmcnt(0)" ::: "memory");  // my frag reads delivered
    __builtin_amdgcn_s_barrier();                        // everyone's
    if (t < 23) stageB(t + 1);                           // overwrite B buffer

    __builtin_amdgcn_s_setprio(1);
#pragma unroll
    for (int i = 0; i < 4; i++)
#pragma unroll
      for (int j = 0; j < 9; j++)
        acc[i][j] = __builtin_amdgcn_mfma_f32_16x16x32_bf16(af[i], bfr[j], acc[i][j], 0, 0, 0);
    __builtin_amdgcn_s_setprio(0);

    asm volatile("s_waitcnt vmcnt(0)" ::: "memory");  // tile t+1 landed
    __builtin_amdgcn_s_barrier();
  }

  // ---- epilogue: scale; repack whole 128x288 tile via LDS [128][296]
  const float kscale = 1.8946361f;  // ln(1+e)/ln2
  float scl[9];
#pragma unroll
  for (int j = 0; j < 9; j++) {
    int gcol = n0 + wc * 144 + j * 16 + lr;
    float s;
    if (gcol < 1536) s = 0.10411754f * log1pf(expf(pds[gcol % 192]));
    else if (gcol < 3072) s = kscale;
    else s = 1.0f;
    scl[j] = s;
  }
#pragma unroll
  for (int i = 0; i < 4; i++)
#pragma unroll
    for (int j = 0; j < 9; j++) {
      int row = wr * 64 + i * 16 + lkq * 4;
      int col = wc * 144 + j * 16 + lr;
#pragma unroll
      for (int r = 0; r < 4; r++)
        smem[(row + r) * 296 + col] = f2bf(acc[i][j][r] * scl[j]);
    }
  asm volatile("s_waitcnt lgkmcnt(0)" ::: "memory");
  __builtin_amdgcn_s_barrier();
#pragma unroll
  for (int p = 0; p < 18; p++) {
    int idx2 = p * 256 + tid;           // 4608 chunks of 16B
    int row = idx2 / 36, cq = idx2 % 36;
    *(uint4*)&C[(size_t)(m0 + row) * 4608 + n0 + cq * 8] =
        *(const uint4*)&smem[row * 296 + cq * 8];
  }
}

// ---------------------------------------------------------------------------
// bdall[t,h,f] = q[t,h,:] . sembbf[f,h,:]  (f<13), via 16x16x32 MFMA.
// ---------------------------------------------------------------------------
__global__ __launch_bounds__(512) void qsemb(const u16* __restrict__ qkv,
                                             const u16* __restrict__ sembbf,
                                             float* __restrict__ bdall) {
  int tid = threadIdx.x;
  int lane = tid & 63;
  int h = tid >> 6;
  int t0 = blockIdx.x * 16;
  int arow = lane & 15, ak = lane >> 4;

  const u16* qp = qkv + (size_t)(t0 + arow) * 4608 + h * 192 + ak * 8;
  const u16* sp = sembbf + (size_t)(lane & 15) * 1536 + h * 192 + ak * 8;

  f32x4 acc = (f32x4){0.f, 0.f, 0.f, 0.f};
#pragma unroll
  for (int kt = 0; kt < 6; kt++) {
    bf16x8 a = *(const bf16x8*)(qp + kt * 32);
    bf16x8 bb = *(const bf16x8*)(sp + kt * 32);
    acc = __builtin_amdgcn_mfma_f32_16x16x32_bf16(a, bb, acc, 0, 0, 0);
  }
  int f = lane & 15;
  int rbase = (lane >> 4) * 4;
  if (f < 13) {
#pragma unroll
    for (int r = 0; r < 4; r++)
      bdall[(size_t)(t0 + rbase + r) * 104 + h * 13 + f] = acc[r];
  }
}

// ---------------------------------------------------------------------------
// Attention, band form: one block per (b, u2, h) covering TWO chunks
// (24 queries, 36 ctx rows). Band softmax (13-wide) == reference 24-wide
// softmax exactly (off-band terms are 0 in f32 after max-subtract).
// ---------------------------------------------------------------------------
__global__ __launch_bounds__(256) void attn_kernel(const u16* __restrict__ qkv,
                                                   const float* __restrict__ bdall,
                                                   const unsigned char* __restrict__ mask,
                                                   float* __restrict__ out) {
  __shared__ u16 sq[24 * 200];
  __shared__ u16 sk[36 * 200];
  __shared__ u16 sv[36 * 200];
  __shared__ float lg[24 * 14];
  __shared__ int vld[36];

  int bid = blockIdx.x;
  int h = bid & 7;
  int u2 = (bid >> 3) % 86;
  int b = bid / (86 * 8);
  int tid = threadIdx.x;
  int tbase = u2 * 24;  // t_q = tbase + w;  t_c = tbase + c - 12

  if (tid < 36) {
    int t = tbase + tid - 12;
    vld[tid] = (t >= 0 && t < 2048 && mask[b * 2048 + t] == 0) ? 1 : 0;
  }

  const u16* base = qkv + (size_t)b * 2048 * 4608 + h * 192;
  for (int idx = tid; idx < 576; idx += 256) {  // q: 24 rows x 24 uint4
    int w = idx / 24, g = idx % 24;
    int t = tbase + w;
    uint4 val = {0u, 0u, 0u, 0u};
    if (t < 2048) val = *(const uint4*)(base + (size_t)t * 4608 + g * 8);
    *(uint4*)&sq[w * 200 + g * 8] = val;
  }
  for (int idx = tid; idx < 1728; idx += 256) {  // k,v: 36 rows x 24 uint4 each
    int kv = idx / 864, r = idx % 864;
    int c = r / 24, g = r % 24;
    int t = tbase + c - 12;
    uint4 val = {0u, 0u, 0u, 0u};
    if (t >= 0 && t < 2048)
      val = *(const uint4*)(base + (size_t)t * 4608 + (kv ? 3072 : 1536) + g * 8);
    if (kv) *(uint4*)&sv[c * 200 + g * 8] = val;
    else    *(uint4*)&sk[c * 200 + g * 8] = val;
  }
  __syncthreads();

  for (int idx = tid; idx < 312; idx += 256) {  // logits: 24 w x 13 f
    int w = idx % 24, f = idx / 24;
    int c = w + f;
    int t = tbase + w;
    float l = -1e9f;
    if (vld[c] && t < 2048) {
      float ac = 0.f;
      const u16* qp = &sq[w * 200];
      const u16* kp = &sk[c * 200];
#pragma unroll 4
      for (int i = 0; i < 24; i++) {
        uint4 qa = *(const uint4*)(qp + i * 8);
        uint4 kb = *(const uint4*)(kp + i * 8);
        ac = fmaf(bfl(qa.x), bfl(kb.x), ac);
        ac = fmaf(bfh(qa.x), bfh(kb.x), ac);
        ac = fmaf(bfl(qa.y), bfl(kb.y), ac);
        ac = fmaf(bfh(qa.y), bfh(kb.y), ac);
        ac = fmaf(bfl(qa.z), bfl(kb.z), ac);
        ac = fmaf(bfh(qa.z), bfh(kb.z), ac);
        ac = fmaf(bfl(qa.w), bfl(kb.w), ac);
        ac = fmaf(bfh(qa.w), bfh(kb.w), ac);
      }
      float bd = bdall[(size_t)(b * 2048 + t) * 104 + h * 13 + f];
      l = tanhf((ac + bd) * 0.02f) * 50.f;  // softcap
    }
    lg[w * 14 + f] = l;
  }
  __syncthreads();

  if (tid < 24) {  // band softmax (13 wide)
    float m = -3e38f;
#pragma unroll
    for (int f = 0; f < 13; f++) m = fmaxf(m, lg[tid * 14 + f]);
    float s = 0.f;
#pragma unroll
    for (int f = 0; f < 13; f++) {
      float e = expf(lg[tid * 14 + f] - m);
      lg[tid * 14 + f] = e;
      s += e;
    }
    float inv = 1.f / s;
#pragma unroll
    for (int f = 0; f < 13; f++) lg[tid * 14 + f] *= inv;
  }
  __syncthreads();

  for (int idx = tid; idx < 1152; idx += 256) {  // PV: 24 w x 48 chunks, 13-term
    int w = idx / 48, g = idx % 48;
    int t = tbase + w;
    if (t >= 2048) continue;
    float a0 = 0, a1 = 0, a2 = 0, a3 = 0;
#pragma unroll
    for (int f = 0; f < 13; f++) {
      float p = lg[w * 14 + f];
      uint2 vv = *(const uint2*)&sv[(w + f) * 200 + g * 4];
      a0 = fmaf(p, bfl(vv.x), a0);
      a1 = fmaf(p, bfh(vv.x), a1);
      a2 = fmaf(p, bfl(vv.y), a2);
      a3 = fmaf(p, bfh(vv.y), a3);
    }
    float4 o = {a0, a1, a2, a3};
    *(float4*)&out[(((size_t)(b * 2048 + t)) * 8 + h) * 192 + g * 4] = o;
  }
}

// ---------------------------------------------------------------------------
extern "C" void kernel_launch(void* const* d_in, const int* in_sizes, int n_in,
                              void* d_out, int out_size, void* d_ws, size_t ws_size,
                              hipStream_t stream) {
  (void)in_sizes; (void)n_in; (void)out_size; (void)ws_size;
  const float* x = (const float*)d_in[0];
  const unsigned char* mask = (const unsigned char*)d_in[1];
  const float* Wqkv = (const float*)d_in[3];
  const float* Wpos = (const float*)d_in[4];
  const float* pds = (const float*)d_in[5];
  float* out = (float*)d_out;

  char* ws = (char*)d_ws;
  u16* Wt = (u16*)ws;                          // 14,155,776 B
  u16* qkv = (u16*)(ws + 14155776);            // 150,994,944 B
  u16* Xb = (u16*)(ws + 165150720);            // 50,331,648 B
  u16* sembbf = (u16*)(ws + 215482368);        // 49,152 B
  float* bdall = (float*)(ws + 215531520);     // 6,815,744 B
  float* part = (float*)(ws + 222347264);      // 3,833,856 B

  transp_wt<<<1728, 256, 0, stream>>>(Wqkv, Wt);
  conv_x<<<12288, 256, 0, stream>>>(x, Xb);
  pos_emb_part<<<288, 256, 0, stream>>>(Wpos, part);
  pos_emb_red<<<96, 256, 0, stream>>>(part, sembbf);
  gemm_qkv<<<2048, 256, 75776, stream>>>(Xb, Wt, qkv, pds);
  qsemb<<<1024, 512, 0, stream>>>(qkv, sembbf, bdall);
  attn_kernel<<<5504, 256, 0, stream>>>(qkv, bdall, mask, out);
}

// Round 14
// 347.432 us; speedup vs baseline: 1.0122x; 1.0122x over previous
//
#include <hip/hip_runtime.h>

typedef unsigned int u32;
typedef unsigned short u16;

typedef __attribute__((ext_vector_type(8))) short bf16x8;
typedef __attribute__((ext_vector_type(4))) float f32x4;

__device__ __forceinline__ u16 f2bf(float f) {
  u32 u = __builtin_bit_cast(u32, f);
  u32 r = (u + 0x7fffu + ((u >> 16) & 1u)) >> 16;  // RNE
  return (u16)r;
}
__device__ __forceinline__ float bfl(u32 u) { return __builtin_bit_cast(float, u << 16); }
__device__ __forceinline__ float bfh(u32 u) { return __builtin_bit_cast(float, u & 0xffff0000u); }

__device__ __forceinline__ void gload_lds16(const u16* g, u16* l) {
  __builtin_amdgcn_global_load_lds(
      (const __attribute__((address_space(1))) void*)g,
      (__attribute__((address_space(3))) void*)l, 16, 0, 0);
}

// ---------------------------------------------------------------------------
// W_qkv [1536,4608] f32 -> Wt [4608,1536] bf16  (64x64 tiles, float4 I/O)
// ---------------------------------------------------------------------------
__global__ __launch_bounds__(256) void transp_wt(const float* __restrict__ W,
                                                 u16* __restrict__ Wt) {
  __shared__ float tile[64][68];
  int bk = blockIdx.x % 24, bn = blockIdx.x / 24;
  int k0 = bk * 64, n0 = bn * 64;
  int tid = threadIdx.x;
#pragma unroll
  for (int p = 0; p < 4; p++) {
    int idx = p * 256 + tid;
    int r = idx >> 4, c4 = idx & 15;
    *(float4*)&tile[r][c4 * 4] = *(const float4*)&W[(size_t)(k0 + r) * 4608 + n0 + c4 * 4];
  }
  __syncthreads();
#pragma unroll
  for (int p = 0; p < 2; p++) {
    int idx = p * 256 + tid;
    int rn = idx >> 3, kc = idx & 7;
    u16 pk[8];
#pragma unroll
    for (int e = 0; e < 8; e++) pk[e] = f2bf(tile[kc * 8 + e][rn]);
    *(uint4*)&Wt[(size_t)(n0 + rn) * 1536 + k0 + kc * 8] = *(const uint4*)pk;
  }
}

// ---------------------------------------------------------------------------
// X [16384*1536] f32 -> bf16
// ---------------------------------------------------------------------------
__global__ __launch_bounds__(256) void conv_x(const float* __restrict__ X,
                                              u16* __restrict__ Xb) {
  int i = blockIdx.x * 256 + threadIdx.x;
  const float4* xp = (const float4*)X;
  float4 a = xp[i * 2], b = xp[i * 2 + 1];
  uint4 o;
  o.x = (u32)f2bf(a.x) | ((u32)f2bf(a.y) << 16);
  o.y = (u32)f2bf(a.z) | ((u32)f2bf(a.w) << 16);
  o.z = (u32)f2bf(b.x) | ((u32)f2bf(b.y) << 16);
  o.w = (u32)f2bf(b.z) | ((u32)f2bf(b.w) << 16);
  ((uint4*)Xb)[i] = o;
}

// ---------------------------------------------------------------------------
// pos-emb stage 1: partial sums over 32-wide k-slices; W_pos read ONCE.
// ---------------------------------------------------------------------------
__global__ __launch_bounds__(256) void pos_emb_part(const float* __restrict__ Wp,
                                                    float* __restrict__ part) {
  __shared__ float er[13 * 32];
  int ks = blockIdx.x % 48, nb = blockIdx.x / 48;
  int tid = threadIdx.x;
  int n = nb * 256 + tid;
  const float cfreq = 9.210340371976184f / 767.0f;  // ln(10000)/(nts-1)
  for (int i = tid; i < 13 * 32; i += 256) {  // strided (R6 bug lesson)
    int f = i >> 5, kk = i & 31;
    int k = ks * 32 + kk;
    int ii = (k < 768) ? k : (k - 768);
    float fr = expf(-cfreq * (float)ii);
    float st = (float)(12 - f) * fr;
    er[f * 32 + kk] = (k < 768) ? sinf(st) : cosf(st);
  }
  __syncthreads();
  float acc[13];
#pragma unroll
  for (int f = 0; f < 13; f++) acc[f] = 0.f;
  const float* wp = Wp + (size_t)(ks * 32) * 1536 + n;
  for (int kk = 0; kk < 32; kk++) {
    float w = wp[(size_t)kk * 1536];
#pragma unroll
    for (int f = 0; f < 13; f++) acc[f] = fmaf(er[f * 32 + kk], w, acc[f]);
  }
#pragma unroll
  for (int f = 0; f < 13; f++)
    part[((size_t)ks * 13 + f) * 1536 + n] = acc[f];
}

// ---------------------------------------------------------------------------
// pos-emb stage 2: reduce 48 slices -> sembbf [16,1536] bf16 (rows 13..15 = 0)
// ---------------------------------------------------------------------------
__global__ __launch_bounds__(256) void pos_emb_red(const float* __restrict__ part,
                                                   u16* __restrict__ sembbf) {
  int idxg = blockIdx.x * 256 + threadIdx.x;  // < 24576
  int f = idxg / 1536, n = idxg % 1536;
  float s = 0.f;
  if (f < 13)
    for (int ks = 0; ks < 48; ks++)
      s += part[((size_t)ks * 13 + f) * 1536 + n];
  sembbf[idxg] = f2bf(s);
}

// ---------------------------------------------------------------------------
// qkv = Xb @ Wt^T : R12 config, BANKED (best measured: 220.5 us, MfmaUtil
// 48.5% = 53.8% LDS-model ceiling x 90% grid occupancy; R13's exact-round
// variant regressed to 47%). block 256x128, 4 waves (2Mx2N -> wave 128x64),
// BK=64; LDS 64 KB (A single-buf 32 KB + B dbuf 2x16 KB) -> 2 blocks/CU;
// proven 128-B-row XOR swizzle; grid 64bm x 36bn = 2304 (4.5 rounds at 2/CU).
// ---------------------------------------------------------------------------
__global__ __launch_bounds__(256, 2) void gemm_qkv(const u16* __restrict__ Xb,
                                                   const u16* __restrict__ Bt,
                                                   u16* __restrict__ C,
                                                   const float* __restrict__ pds) {
  extern __shared__ u16 smem[];  // A @0 (16384 u16) | B @16384 + (t&1)*8192

  const int tid = threadIdx.x;   // 0..255
  const int lane = tid & 63;
  const int wv = tid >> 6;       // 0..3
  const int wr = wv >> 1;        // 0..1  m-half (128 rows)
  const int wc = wv & 1;         // 0..1  n-half (64 cols)
  const int lr = lane & 15;
  const int lkq = lane >> 4;     // 0..3
  const int sx = lr & 7;         // proven swizzle (R5/R8/R9/R12)

  // 2304 blocks = 8 xcd x (8 bm x 36 bn), bn fastest
  int bid = blockIdx.x;
  int xcd = bid & 7, idx = bid >> 3;
  int bm = xcd * 8 + idx / 36;
  int bn = idx % 36;
  int m0 = bm * 256, n0 = bn * 128;

  auto stageA = [&](int T) {  // 256 rows x 8 chunks = 2048, 8 loads/thread
#pragma unroll
    for (int q = 0; q < 8; q++) {
      int ch = q * 256 + tid;
      int r = ch >> 3, cr = ch & 7;
      int crs = cr ^ (r & 7);
      gload_lds16(Xb + (size_t)(m0 + r) * 1536 + T * 64 + crs * 8, smem + ch * 8);
    }
  };
  auto stageB = [&](int T) {  // 128 rows x 8 chunks = 1024, 4 loads/thread
#pragma unroll
    for (int q = 0; q < 4; q++) {
      int ch = q * 256 + tid;
      int r = ch >> 3, cr = ch & 7;
      int crs = cr ^ (r & 7);
      gload_lds16(Bt + (size_t)(n0 + r) * 1536 + T * 64 + crs * 8,
                  smem + 16384 + (T & 1) * 8192 + ch * 8);
    }
  };

  f32x4 acc[8][4];
#pragma unroll
  for (int i = 0; i < 8; i++)
#pragma unroll
    for (int j = 0; j < 4; j++) acc[i][j] = (f32x4){0.f, 0.f, 0.f, 0.f};

  stageA(0); stageB(0);
  asm volatile("s_waitcnt vmcnt(0)" ::: "memory");
  __builtin_amdgcn_s_barrier();

  for (int t = 0; t < 24; t++) {
    const int bb = 16384 + (t & 1) * 8192;

    // ---- A frags, BOTH ks (A buf about to be overwritten)
    bf16x8 af[16], bfr[4];
#pragma unroll
    for (int i = 0; i < 8; i++) {
      int R = wr * 128 + i * 16 + lr;
      af[i * 2 + 0] = *(const bf16x8*)&smem[R * 64 + (lkq ^ sx) * 8];
      af[i * 2 + 1] = *(const bf16x8*)&smem[R * 64 + ((4 + lkq) ^ sx) * 8];
    }
    asm volatile("s_waitcnt lgkmcnt(0)" ::: "memory");  // my A reads delivered
    __builtin_amdgcn_s_barrier();                        // everyone's
    if (t < 23) { stageA(t + 1); stageB(t + 1); }        // A-buf + parity t+1

    // ---- ks0: B frags from parity t (not touched by staging), MFMA
#pragma unroll
    for (int j = 0; j < 4; j++) {
      int R = wc * 64 + j * 16 + lr;
      bfr[j] = *(const bf16x8*)&smem[bb + R * 64 + (lkq ^ sx) * 8];
    }
    __builtin_amdgcn_s_setprio(1);
#pragma unroll
    for (int i = 0; i < 8; i++)
#pragma unroll
      for (int j = 0; j < 4; j++)
        acc[i][j] = __builtin_amdgcn_mfma_f32_16x16x32_bf16(af[i * 2], bfr[j], acc[i][j], 0, 0, 0);
    __builtin_amdgcn_s_setprio(0);

    // ---- ks1
#pragma unroll
    for (int j = 0; j < 4; j++) {
      int R = wc * 64 + j * 16 + lr;
      bfr[j] = *(const bf16x8*)&smem[bb + R * 64 + ((4 + lkq) ^ sx) * 8];
    }
    __builtin_amdgcn_s_setprio(1);
#pragma unroll
    for (int i = 0; i < 8; i++)
#pragma unroll
      for (int j = 0; j < 4; j++)
        acc[i][j] = __builtin_amdgcn_mfma_f32_16x16x32_bf16(af[i * 2 + 1], bfr[j], acc[i][j], 0, 0, 0);
    __builtin_amdgcn_s_setprio(0);

    asm volatile("s_waitcnt vmcnt(0)" ::: "memory");  // tile t+1 landed
    __builtin_amdgcn_s_barrier();
  }

  // ---- epilogue: scale; repack+store two 128-row halves via LDS [128][136]
  const float kscale = 1.8946361f;  // ln(1+e)/ln2
  float scl[4];
#pragma unroll
  for (int j = 0; j < 4; j++) {
    int gcol = n0 + wc * 64 + j * 16 + lr;
    float s;
    if (gcol < 1536) s = 0.10411754f * log1pf(expf(pds[gcol % 192]));
    else if (gcol < 3072) s = kscale;
    else s = 1.0f;
    scl[j] = s;
  }
#pragma unroll
  for (int h = 0; h < 2; h++) {
    if (wr == h) {  // the 2 waves holding rows [h*128, h*128+128)
#pragma unroll
      for (int i = 0; i < 8; i++)
#pragma unroll
        for (int j = 0; j < 4; j++) {
          int row = i * 16 + lkq * 4;
          int col = wc * 64 + j * 16 + lr;
#pragma unroll
          for (int r = 0; r < 4; r++)
            smem[(row + r) * 136 + col] = f2bf(acc[i][j][r] * scl[j]);
        }
    }
    asm volatile("s_waitcnt lgkmcnt(0)" ::: "memory");
    __builtin_amdgcn_s_barrier();
#pragma unroll
    for (int p = 0; p < 8; p++) {
      int idx2 = p * 256 + tid;           // 2048 chunks of 16B
      int row = idx2 >> 4, cq = idx2 & 15;
      *(uint4*)&C[(size_t)(m0 + h * 128 + row) * 4608 + n0 + cq * 8] =
          *(const uint4*)&smem[row * 136 + cq * 8];
    }
    __builtin_amdgcn_s_barrier();  // half-h LDS reads done before half-(h+1) writes
  }
}

// ---------------------------------------------------------------------------
// bdall[t,h,f] = q[t,h,:] . sembbf[f,h,:]  (f<13), via 16x16x32 MFMA.
// ---------------------------------------------------------------------------
__global__ __launch_bounds__(512) void qsemb(const u16* __restrict__ qkv,
                                             const u16* __restrict__ sembbf,
                                             float* __restrict__ bdall) {
  int tid = threadIdx.x;
  int lane = tid & 63;
  int h = tid >> 6;
  int t0 = blockIdx.x * 16;
  int arow = lane & 15, ak = lane >> 4;

  const u16* qp = qkv + (size_t)(t0 + arow) * 4608 + h * 192 + ak * 8;
  const u16* sp = sembbf + (size_t)(lane & 15) * 1536 + h * 192 + ak * 8;

  f32x4 acc = (f32x4){0.f, 0.f, 0.f, 0.f};
#pragma unroll
  for (int kt = 0; kt < 6; kt++) {
    bf16x8 a = *(const bf16x8*)(qp + kt * 32);
    bf16x8 bb = *(const bf16x8*)(sp + kt * 32);
    acc = __builtin_amdgcn_mfma_f32_16x16x32_bf16(a, bb, acc, 0, 0, 0);
  }
  int f = lane & 15;
  int rbase = (lane >> 4) * 4;
  if (f < 13) {
#pragma unroll
    for (int r = 0; r < 4; r++)
      bdall[(size_t)(t0 + rbase + r) * 104 + h * 13 + f] = acc[r];
  }
}

// ---------------------------------------------------------------------------
// Attention, band form: one block per (b, u2, h) covering TWO chunks
// (24 queries, 36 ctx rows). Band softmax (13-wide) == reference 24-wide
// softmax exactly (off-band terms are 0 in f32 after max-subtract).
// R14: dual-accumulator logits dot (halves serial fma chain), lg stride 16.
// ---------------------------------------------------------------------------
__global__ __launch_bounds__(256) void attn_kernel(const u16* __restrict__ qkv,
                                                   const float* __restrict__ bdall,
                                                   const unsigned char* __restrict__ mask,
                                                   float* __restrict__ out) {
  __shared__ u16 sq[24 * 200];
  __shared__ u16 sk[36 * 200];
  __shared__ u16 sv[36 * 200];
  __shared__ float lg[24 * 16];
  __shared__ int vld[36];

  int bid = blockIdx.x;
  int h = bid & 7;
  int u2 = (bid >> 3) % 86;
  int b = bid / (86 * 8);
  int tid = threadIdx.x;
  int tbase = u2 * 24;  // t_q = tbase + w;  t_c = tbase + c - 12

  if (tid < 36) {
    int t = tbase + tid - 12;
    vld[tid] = (t >= 0 && t < 2048 && mask[b * 2048 + t] == 0) ? 1 : 0;
  }

  const u16* base = qkv + (size_t)b * 2048 * 4608 + h * 192;
  for (int idx = tid; idx < 576; idx += 256) {  // q: 24 rows x 24 uint4
    int w = idx / 24, g = idx % 24;
    int t = tbase + w;
    uint4 val = {0u, 0u, 0u, 0u};
    if (t < 2048) val = *(const uint4*)(base + (size_t)t * 4608 + g * 8);
    *(uint4*)&sq[w * 200 + g * 8] = val;
  }
  for (int idx = tid; idx < 1728; idx += 256) {  // k,v: 36 rows x 24 uint4 each
    int kv = idx / 864, r = idx % 864;
    int c = r / 24, g = r % 24;
    int t = tbase + c - 12;
    uint4 val = {0u, 0u, 0u, 0u};
    if (t >= 0 && t < 2048)
      val = *(const uint4*)(base + (size_t)t * 4608 + (kv ? 3072 : 1536) + g * 8);
    if (kv) *(uint4*)&sv[c * 200 + g * 8] = val;
    else    *(uint4*)&sk[c * 200 + g * 8] = val;
  }
  __syncthreads();

  for (int idx = tid; idx < 312; idx += 256) {  // logits: 24 w x 13 f
    int w = idx % 24, f = idx / 24;
    int c = w + f;
    int t = tbase + w;
    float l = -1e9f;
    if (vld[c] && t < 2048) {
      float ac0 = 0.f, ac1 = 0.f;  // dual chains: halve dependent-fma latency
      const u16* qp = &sq[w * 200];
      const u16* kp = &sk[c * 200];
#pragma unroll 4
      for (int i = 0; i < 24; i++) {
        uint4 qa = *(const uint4*)(qp + i * 8);
        uint4 kb = *(const uint4*)(kp + i * 8);
        ac0 = fmaf(bfl(qa.x), bfl(kb.x), ac0);
        ac1 = fmaf(bfh(qa.x), bfh(kb.x), ac1);
        ac0 = fmaf(bfl(qa.y), bfl(kb.y), ac0);
        ac1 = fmaf(bfh(qa.y), bfh(kb.y), ac1);
        ac0 = fmaf(bfl(qa.z), bfl(kb.z), ac0);
        ac1 = fmaf(bfh(qa.z), bfh(kb.z), ac1);
        ac0 = fmaf(bfl(qa.w), bfl(kb.w), ac0);
        ac1 = fmaf(bfh(qa.w), bfh(kb.w), ac1);
      }
      float bd = bdall[(size_t)(b * 2048 + t) * 104 + h * 13 + f];
      l = tanhf((ac0 + ac1 + bd) * 0.02f) * 50.f;  // softcap
    }
    lg[(w << 4) | f] = l;
  }
  __syncthreads();

  if (tid < 24) {  // band softmax (13 wide)
    float m = -3e38f;
#pragma unroll
    for (int f = 0; f < 13; f++) m = fmaxf(m, lg[(tid << 4) | f]);
    float s = 0.f;
#pragma unroll
    for (int f = 0; f < 13; f++) {
      float e = expf(lg[(tid << 4) | f] - m);
      lg[(tid << 4) | f] = e;
      s += e;
    }
    float inv = 1.f / s;
#pragma unroll
    for (int f = 0; f < 13; f++) lg[(tid << 4) | f] *= inv;
  }
  __syncthreads();

  for (int idx = tid; idx < 1152; idx += 256) {  // PV: 24 w x 48 chunks, 13-term
    int w = idx / 48, g = idx % 48;
    int t = tbase + w;
    if (t >= 2048) continue;
    const float* lp = &lg[w << 4];
    const u16* vp = &sv[w * 200 + g * 4];
    float a0 = 0, a1 = 0, a2 = 0, a3 = 0;
#pragma unroll
    for (int f = 0; f < 13; f++) {
      float p = lp[f];
      uint2 vv = *(const uint2*)(vp + f * 200);
      a0 = fmaf(p, bfl(vv.x), a0);
      a1 = fmaf(p, bfh(vv.x), a1);
      a2 = fmaf(p, bfl(vv.y), a2);
      a3 = fmaf(p, bfh(vv.y), a3);
    }
    float4 o = {a0, a1, a2, a3};
    *(float4*)&out[(((size_t)(b * 2048 + t)) * 8 + h) * 192 + g * 4] = o;
  }
}

// ---------------------------------------------------------------------------
extern "C" void kernel_launch(void* const* d_in, const int* in_sizes, int n_in,
                              void* d_out, int out_size, void* d_ws, size_t ws_size,
                              hipStream_t stream) {
  (void)in_sizes; (void)n_in; (void)out_size; (void)ws_size;
  const float* x = (const float*)d_in[0];
  const unsigned char* mask = (const unsigned char*)d_in[1];
  const float* Wqkv = (const float*)d_in[3];
  const float* Wpos = (const float*)d_in[4];
  const float* pds = (const float*)d_in[5];
  float* out = (float*)d_out;

  char* ws = (char*)d_ws;
  u16* Wt = (u16*)ws;                          // 14,155,776 B
  u16* qkv = (u16*)(ws + 14155776);            // 150,994,944 B
  u16* Xb = (u16*)(ws + 165150720);            // 50,331,648 B
  u16* sembbf = (u16*)(ws + 215482368);        // 49,152 B
  float* bdall = (float*)(ws + 215531520);     // 6,815,744 B
  float* part = (float*)(ws + 222347264);      // 3,833,856 B

  transp_wt<<<1728, 256, 0, stream>>>(Wqkv, Wt);
  conv_x<<<12288, 256, 0, stream>>>(x, Xb);
  pos_emb_part<<<288, 256, 0, stream>>>(Wpos, part);
  pos_emb_red<<<96, 256, 0, stream>>>(part, sembbf);
  gemm_qkv<<<2304, 256, 65536, stream>>>(Xb, Wt, qkv, pds);
  qsemb<<<1024, 512, 0, stream>>>(qkv, sembbf, bdall);
  attn_kernel<<<5504, 256, 0, stream>>>(qkv, bdall, mask, out);
}